// Round 7
// baseline (1376.862 us; speedup 1.0000x reference)
//
#include <hip/hip_runtime.h>
#include <hip/hip_bf16.h>

#define NN 50000
#define EE 1200000
#define GG 256
#define LL 5

// fast silu
__device__ __forceinline__ float silu_f(float x) {
    return x * __builtin_amdgcn_rcpf(1.0f + __expf(-x));
}
__device__ __forceinline__ int rfl(int x) { return __builtin_amdgcn_readfirstlane(x); }

// ---------- CSR build ----------
// hist also records each edge's within-row position (coalesced write) so scatter needs no atomic.
__global__ __launch_bounds__(256) void k_hist(const int* __restrict__ ei, int* __restrict__ fill,
                                              int* __restrict__ posb, int E) {
    int e = blockIdx.x * 256 + threadIdx.x;
    if (e < E) posb[e] = atomicAdd(&fill[ei[E + e]], 1);
}

__global__ __launch_bounds__(256) void k_scan_blk(int* __restrict__ fill, int* __restrict__ rowptr,
                                                  float* __restrict__ degf, int* __restrict__ bsum, int n) {
    __shared__ int wsum[4];
    int tid = threadIdx.x, lane = tid & 63, wid = tid >> 6;
    int i = blockIdx.x * 256 + tid;
    int v = (i < n) ? fill[i] : 0;
    int x = v;
    #pragma unroll
    for (int off = 1; off < 64; off <<= 1) {
        int t = __shfl_up(x, off);
        if (lane >= off) x += t;
    }
    if (lane == 63) wsum[wid] = x;
    __syncthreads();
    int waveoff = 0;
    if (wid > 0) waveoff += wsum[0];
    if (wid > 1) waveoff += wsum[1];
    if (wid > 2) waveoff += wsum[2];
    int inc = x + waveoff;
    if (i < n) {
        rowptr[i + 1] = inc;
        degf[i] = (float)(v > 0 ? v : 1);
    }
    if (tid == 255) bsum[blockIdx.x] = inc;
}

__global__ __launch_bounds__(256) void k_scan_top(int* __restrict__ bsum, int B) {
    __shared__ int wsum[4];
    int tid = threadIdx.x, lane = tid & 63, wid = tid >> 6;
    int v = (tid < B) ? bsum[tid] : 0;
    int x = v;
    #pragma unroll
    for (int off = 1; off < 64; off <<= 1) {
        int t = __shfl_up(x, off);
        if (lane >= off) x += t;
    }
    if (lane == 63) wsum[wid] = x;
    __syncthreads();
    int waveoff = 0;
    if (wid > 0) waveoff += wsum[0];
    if (wid > 1) waveoff += wsum[1];
    if (wid > 2) waveoff += wsum[2];
    if (tid < B) bsum[tid] = x + waveoff;
}

__global__ __launch_bounds__(256) void k_scan_add(const int* __restrict__ bsum, int* __restrict__ rowptr, int n) {
    int b = blockIdx.x;
    int i = b * 256 + threadIdx.x;
    if (i < n) {
        int add = (b > 0) ? bsum[b - 1] : 0;
        rowptr[i + 1] += add;
    }
    if (i == 0) rowptr[0] = 0;
}

// atomic-free scatter; nontemporal store for the random edata write
__global__ __launch_bounds__(256) void k_scatter(const int* __restrict__ ei, const float* __restrict__ ea,
                                                 const int* __restrict__ rowptr, const int* __restrict__ posb,
                                                 unsigned int* __restrict__ edata, int E) {
    int e = blockIdx.x * 256 + threadIdx.x;
    if (e < E) {
        int d = ei[E + e];
        int idx = rowptr[d] + posb[e];
        int ea15 = (int)(ea[e] * 32768.0f + 0.5f);
        if (ea15 > 32767) ea15 = 32767;
        unsigned int v = ((unsigned int)ea15 << 17) | (unsigned int)ei[e];
        __builtin_nontemporal_store(v, &edata[idx]);
    }
}

// ---------- weight fold ----------
__global__ __launch_bounds__(256) void k_fold(const float* __restrict__ msg_W2, const float* __restrict__ msg_b2,
                                              const float* __restrict__ upd_W, float* __restrict__ W2p,
                                              float* __restrict__ b2p) {
    int l = blockIdx.x;
    const float* W2 = msg_W2 + (size_t)l * 4096;
    const float* U2 = upd_W + (size_t)l * 8192 + 4096;
    int lane = threadIdx.x & 63, wid = threadIdx.x >> 6;
    for (int ii = 0; ii < 16; ii++) {
        int i = rfl(wid * 16 + ii);
        float acc = 0.0f;
        for (int k = 0; k < 64; k++) acc = fmaf(W2[i * 64 + k], U2[k * 64 + lane], acc);
        W2p[(size_t)l * 4096 + i * 64 + lane] = acc;
    }
    if (wid == 0) {
        float acc = 0.0f;
        for (int k = 0; k < 64; k++) acc = fmaf(msg_b2[l * 64 + k], U2[k * 64 + lane], acc);
        b2p[l * 64 + lane] = acc;
    }
}

// ---------- node embedding: coalesced x staging via LDS ----------
__global__ __launch_bounds__(256) void k_node_emb(const float* __restrict__ x, const float* __restrict__ W,
                                                  const float* __restrict__ b, float* __restrict__ h, int n) {
    __shared__ float sW[92 * 64];
    __shared__ float sX[4][736];
    for (int i = threadIdx.x; i < 92 * 64; i += 256) sW[i] = W[i];
    __syncthreads();
    int lane = threadIdx.x & 63, wid = threadIdx.x >> 6;
    int gw = (blockIdx.x * 256 + threadIdx.x) >> 6;
    int nw = (gridDim.x * 256) >> 6;
    float bj = b[lane];
    int tiles = n >> 3;
    for (int t = gw; t < tiles; t += nw) {
        int rb = rfl(t << 3);
        const float4* xb = (const float4*)(x + (size_t)rb * 92);
        float4* sx4 = (float4*)&sX[wid][0];
        sx4[lane] = xb[lane];
        sx4[lane + 64] = xb[lane + 64];
        if (lane < 56) sx4[lane + 128] = xb[lane + 128];
        float acc[8];
        #pragma unroll
        for (int r = 0; r < 8; r++) acc[r] = bj;
        for (int kb = 0; kb < 80; kb += 16) {
            float wv[16];
            #pragma unroll
            for (int t2 = 0; t2 < 16; t2++) wv[t2] = sW[(kb + t2) * 64 + lane];
            #pragma unroll
            for (int r = 0; r < 8; r++) {
                #pragma unroll
                for (int t2 = 0; t2 < 16; t2++) acc[r] = fmaf(sX[wid][r * 92 + kb + t2], wv[t2], acc[r]);
            }
        }
        {
            float wv[12];
            #pragma unroll
            for (int t2 = 0; t2 < 12; t2++) wv[t2] = sW[(80 + t2) * 64 + lane];
            #pragma unroll
            for (int r = 0; r < 8; r++) {
                #pragma unroll
                for (int t2 = 0; t2 < 12; t2++) acc[r] = fmaf(sX[wid][r * 92 + 80 + t2], wv[t2], acc[r]);
            }
        }
        #pragma unroll
        for (int r = 0; r < 8; r++) h[(size_t)(rb + r) * 64 + lane] = acc[r];
    }
}

// ---------- layer 0 pre: Hd = h@W1[0:64]+b1 (fp32) ; Hs = h@W1[64:128] (fp16); staged h ----------
__global__ __launch_bounds__(256) void k_node_pre(const float* __restrict__ h, const float* __restrict__ W1,
                                                  const float* __restrict__ b1, float* __restrict__ Hd,
                                                  _Float16* __restrict__ Hs, int n) {
    __shared__ float sA[4096], sB[4096];
    __shared__ float sH[4][512];
    for (int i = threadIdx.x; i < 4096; i += 256) { sA[i] = W1[i]; sB[i] = W1[4096 + i]; }
    __syncthreads();
    int lane = threadIdx.x & 63, wid = threadIdx.x >> 6;
    int gw = (blockIdx.x * 256 + threadIdx.x) >> 6;
    int nw = (gridDim.x * 256) >> 6;
    float bj = b1[lane];
    int tiles = n >> 3;
    for (int t = gw; t < tiles; t += nw) {
        int rb = rfl(t << 3);
        const float4* hb = (const float4*)(h + (size_t)rb * 64);
        float4* sh4 = (float4*)&sH[wid][0];
        sh4[lane] = hb[lane];
        sh4[lane + 64] = hb[lane + 64];
        float accA[8], accB[8];
        #pragma unroll
        for (int r = 0; r < 8; r++) { accA[r] = bj; accB[r] = 0.0f; }
        for (int kb = 0; kb < 64; kb += 8) {
            float wA[8], wB[8];
            #pragma unroll
            for (int t2 = 0; t2 < 8; t2++) { wA[t2] = sA[(kb + t2) * 64 + lane]; wB[t2] = sB[(kb + t2) * 64 + lane]; }
            #pragma unroll
            for (int r = 0; r < 8; r++) {
                #pragma unroll
                for (int t2 = 0; t2 < 8; t2++) {
                    float hk = sH[wid][r * 64 + kb + t2];
                    accA[r] = fmaf(hk, wA[t2], accA[r]);
                    accB[r] = fmaf(hk, wB[t2], accB[r]);
                }
            }
        }
        #pragma unroll
        for (int r = 0; r < 8; r++) {
            Hd[(size_t)(rb + r) * 64 + lane] = accA[r];
            Hs[(size_t)(rb + r) * 64 + lane] = (_Float16)accB[r];
        }
    }
}

// ---------- fused BN+SiLU + next-layer pre (layers 1..4) ----------
__global__ __launch_bounds__(256) void k_bn_pre(const float* __restrict__ u, const float* __restrict__ usum,
                                                const float* __restrict__ usq, const float* __restrict__ g,
                                                const float* __restrict__ be, const float* __restrict__ W1,
                                                const float* __restrict__ b1, float* __restrict__ h,
                                                float* __restrict__ Hd, _Float16* __restrict__ Hs,
                                                int n, float invN) {
    __shared__ float sA[4096], sB[4096];
    __shared__ float sH[4][8][64];
    for (int i = threadIdx.x; i < 4096; i += 256) { sA[i] = W1[i]; sB[i] = W1[4096 + i]; }
    __syncthreads();
    int lane = threadIdx.x & 63, wid = threadIdx.x >> 6;
    float mean = usum[lane] * invN;
    float var = usq[lane] * invN - mean * mean;
    float inv = rsqrtf(var + 1e-5f);
    float sc = inv * g[lane];
    float sh = fmaf(-mean, sc, be[lane]);
    float bj = b1[lane];
    int gw = (blockIdx.x * 256 + threadIdx.x) >> 6;
    int nw = (gridDim.x * 256) >> 6;
    int tiles = n >> 3;
    for (int t = gw; t < tiles; t += nw) {
        int rb = rfl(t << 3);
        #pragma unroll
        for (int r = 0; r < 8; r++) {
            float uv = u[(size_t)(rb + r) * 64 + lane];
            float hv = silu_f(fmaf(uv, sc, sh));
            h[(size_t)(rb + r) * 64 + lane] = hv;
            sH[wid][r][lane] = hv;
        }
        float accA[8], accB[8];
        #pragma unroll
        for (int r = 0; r < 8; r++) { accA[r] = bj; accB[r] = 0.0f; }
        for (int k = 0; k < 64; k += 2) {
            float wA0 = sA[k * 64 + lane],       wB0 = sB[k * 64 + lane];
            float wA1 = sA[(k + 1) * 64 + lane], wB1 = sB[(k + 1) * 64 + lane];
            #pragma unroll
            for (int r = 0; r < 8; r++) {
                float h0 = sH[wid][r][k], h1 = sH[wid][r][k + 1];
                accA[r] = fmaf(h0, wA0, accA[r]);
                accB[r] = fmaf(h0, wB0, accB[r]);
                accA[r] = fmaf(h1, wA1, accA[r]);
                accB[r] = fmaf(h1, wB1, accB[r]);
            }
        }
        #pragma unroll
        for (int r = 0; r < 8; r++) {
            Hd[(size_t)(rb + r) * 64 + lane] = accA[r];
            Hs[(size_t)(rb + r) * 64 + lane] = (_Float16)accB[r];
        }
    }
}

// ---------- edge pass 1: sum(z), sum(z^2); 2-deep software-pipelined gather loop ----------
__global__ __launch_bounds__(256) void k_edge_stats(const float* __restrict__ Hd, const _Float16* __restrict__ Hs,
                                                    const int* __restrict__ rowptr, const unsigned int* __restrict__ edata,
                                                    const float* __restrict__ w1e,
                                                    float* __restrict__ esum, float* __restrict__ esq, int n) {
    __shared__ float rs[4][64], rq[4][64];
    int wid = threadIdx.x >> 6, lane = threadIdx.x & 63;
    int gw = (blockIdx.x * 256 + threadIdx.x) >> 6;
    int nw = (gridDim.x * 256) >> 6;
    float wj = w1e[lane] * (1.0f / 32768.0f);
    float s = 0.0f, q = 0.0f;
    for (int node = gw; node < n; node += nw) {
        int nu = rfl(node);
        int e0 = rfl(rowptr[nu]), e1 = rfl(rowptr[nu + 1]);
        if (e0 == e1) continue;
        float hd = Hd[(size_t)nu * 64 + lane];
        int nc = (e1 - e0) >> 3;
        int e = e0 + (nc << 3);
        if (nc > 0) {
            unsigned int pc[8];
            #pragma unroll
            for (int j = 0; j < 8; j++) pc[j] = edata[e0 + j];
            int eb = e0 + 8;
            for (int c = 0; c < nc - 1; c++, eb += 8) {
                float hs[8], av[8];
                #pragma unroll
                for (int j = 0; j < 8; j++) {
                    int sidx = rfl((int)(pc[j] & 0x1FFFFu));
                    av[j] = (float)rfl((int)(pc[j] >> 17));
                    hs[j] = (float)Hs[(size_t)sidx * 64 + lane];
                }
                #pragma unroll
                for (int j = 0; j < 8; j++) pc[j] = edata[eb + j];
                #pragma unroll
                for (int j = 0; j < 8; j++) {
                    float z = fmaf(av[j], wj, hd) + hs[j];
                    s += z;
                    q = fmaf(z, z, q);
                }
            }
            {
                float hs[8], av[8];
                #pragma unroll
                for (int j = 0; j < 8; j++) {
                    int sidx = rfl((int)(pc[j] & 0x1FFFFu));
                    av[j] = (float)rfl((int)(pc[j] >> 17));
                    hs[j] = (float)Hs[(size_t)sidx * 64 + lane];
                }
                #pragma unroll
                for (int j = 0; j < 8; j++) {
                    float z = fmaf(av[j], wj, hd) + hs[j];
                    s += z;
                    q = fmaf(z, z, q);
                }
            }
        }
        for (; e < e1; e++) {
            unsigned int p = edata[e];
            int sidx = rfl((int)(p & 0x1FFFFu));
            float a = (float)rfl((int)(p >> 17));
            float z = fmaf(a, wj, hd) + (float)Hs[(size_t)sidx * 64 + lane];
            s += z;
            q = fmaf(z, z, q);
        }
    }
    rs[wid][lane] = s; rq[wid][lane] = q;
    __syncthreads();
    if (wid == 0) {
        float ts = rs[0][lane] + rs[1][lane] + rs[2][lane] + rs[3][lane];
        float tq = rq[0][lane] + rq[1][lane] + rq[2][lane] + rq[3][lane];
        atomicAdd(&esum[lane], ts);
        atomicAdd(&esq[lane], tq);
    }
}

// ---------- edge pass 2: aggregation ONLY (no LDS -> max occupancy for latency-bound gathers) ----------
__global__ __launch_bounds__(256, 8) void k_edge_agg(const float* __restrict__ Hd, const _Float16* __restrict__ Hs,
                                                     const int* __restrict__ rowptr, const unsigned int* __restrict__ edata,
                                                     const float* __restrict__ w1e,
                                                     const float* __restrict__ esum, const float* __restrict__ esq,
                                                     const float* __restrict__ g1, const float* __restrict__ be1,
                                                     const float* __restrict__ degf, float* __restrict__ sacc,
                                                     int n, float invE) {
    int lane = threadIdx.x & 63;
    float mean = esum[lane] * invE;
    float var = esq[lane] * invE - mean * mean;
    float inv = rsqrtf(var + 1e-5f);
    float sc = inv * g1[lane];
    float sh = fmaf(-mean, sc, be1[lane]);
    float wj = w1e[lane] * (1.0f / 32768.0f);
    int gw = (blockIdx.x * 256 + threadIdx.x) >> 6;
    int nw = (gridDim.x * 256) >> 6;
    for (int node = gw; node < n; node += nw) {
        int nu = rfl(node);
        int e0 = rfl(rowptr[nu]), e1 = rfl(rowptr[nu + 1]);
        float hd = Hd[(size_t)nu * 64 + lane];
        float acc = 0.0f;
        int nc = (e1 - e0) >> 3;
        int e = e0 + (nc << 3);
        if (nc > 0) {
            unsigned int pc[8];
            #pragma unroll
            for (int j = 0; j < 8; j++) pc[j] = edata[e0 + j];
            int eb = e0 + 8;
            for (int c = 0; c < nc - 1; c++, eb += 8) {
                float hs[8], av[8];
                #pragma unroll
                for (int j = 0; j < 8; j++) {
                    int sidx = rfl((int)(pc[j] & 0x1FFFFu));
                    av[j] = (float)rfl((int)(pc[j] >> 17));
                    hs[j] = (float)Hs[(size_t)sidx * 64 + lane];
                }
                #pragma unroll
                for (int j = 0; j < 8; j++) pc[j] = edata[eb + j];
                #pragma unroll
                for (int j = 0; j < 8; j++) {
                    float z = fmaf(av[j], wj, hd) + hs[j];
                    acc += silu_f(fmaf(z, sc, sh));
                }
            }
            {
                float hs[8], av[8];
                #pragma unroll
                for (int j = 0; j < 8; j++) {
                    int sidx = rfl((int)(pc[j] & 0x1FFFFu));
                    av[j] = (float)rfl((int)(pc[j] >> 17));
                    hs[j] = (float)Hs[(size_t)sidx * 64 + lane];
                }
                #pragma unroll
                for (int j = 0; j < 8; j++) {
                    float z = fmaf(av[j], wj, hd) + hs[j];
                    acc += silu_f(fmaf(z, sc, sh));
                }
            }
        }
        for (; e < e1; e++) {
            unsigned int p = edata[e];
            int sidx = rfl((int)(p & 0x1FFFFu));
            float a = (float)rfl((int)(p >> 17));
            float z = fmaf(a, wj, hd) + (float)Hs[(size_t)sidx * 64 + lane];
            acc += silu_f(fmaf(z, sc, sh));
        }
        sacc[(size_t)nu * 64 + lane] = acc / degf[nu];
    }
}

// ---------- node update GEMM: u = h@U1 + sacc@W2p + gate*b2p + ub ; stats(u) ----------
__global__ __launch_bounds__(256) void k_node_upd(const float* __restrict__ h, const float* __restrict__ sacc,
                                                  const int* __restrict__ rowptr,
                                                  const float* __restrict__ U1, const float* __restrict__ W2p,
                                                  const float* __restrict__ b2p, const float* __restrict__ ub,
                                                  float* __restrict__ u, float* __restrict__ usum,
                                                  float* __restrict__ usq, int n) {
    __shared__ float sU[4096], sP[4096];
    __shared__ float2 sHA[4][8][64];
    __shared__ float rs[4][64], rq[4][64];
    for (int i = threadIdx.x; i < 4096; i += 256) { sU[i] = U1[i]; sP[i] = W2p[i]; }
    __syncthreads();
    int lane = threadIdx.x & 63, wid = threadIdx.x >> 6;
    float b2j = b2p[lane], ubj = ub[lane];
    int gw = (blockIdx.x * 256 + threadIdx.x) >> 6;
    int nw = (gridDim.x * 256) >> 6;
    float s = 0.0f, q = 0.0f;
    int tiles = n >> 3;
    for (int t = gw; t < tiles; t += nw) {
        int rb = rfl(t << 3);
        #pragma unroll
        for (int r = 0; r < 8; r++) {
            sHA[wid][r][lane] = make_float2(h[(size_t)(rb + r) * 64 + lane],
                                            sacc[(size_t)(rb + r) * 64 + lane]);
        }
        float accu[8];
        #pragma unroll
        for (int r = 0; r < 8; r++) {
            int c0 = rowptr[rb + r], c1 = rowptr[rb + r + 1];
            accu[r] = fmaf((c1 > c0) ? 1.0f : 0.0f, b2j, ubj);
        }
        for (int k = 0; k < 64; k++) {
            float wU = sU[k * 64 + lane], wP = sP[k * 64 + lane];
            #pragma unroll
            for (int r = 0; r < 8; r++) {
                float2 ha = sHA[wid][r][k];
                accu[r] = fmaf(ha.x, wU, accu[r]);
                accu[r] = fmaf(ha.y, wP, accu[r]);
            }
        }
        #pragma unroll
        for (int r = 0; r < 8; r++) {
            u[(size_t)(rb + r) * 64 + lane] = accu[r];
            s += accu[r];
            q = fmaf(accu[r], accu[r], q);
        }
    }
    rs[wid][lane] = s; rq[wid][lane] = q;
    __syncthreads();
    if (wid == 0) {
        float ts = rs[0][lane] + rs[1][lane] + rs[2][lane] + rs[3][lane];
        float tq = rq[0][lane] + rq[1][lane] + rq[2][lane] + rq[3][lane];
        atomicAdd(&usum[lane], ts);
        atomicAdd(&usq[lane], tq);
    }
}

// ---------- layer-4 BN + SiLU fused with pooling ----------
__global__ __launch_bounds__(256) void k_bn_pool(const float* __restrict__ u, const float* __restrict__ usum,
                                                 const float* __restrict__ usq, const float* __restrict__ g,
                                                 const float* __restrict__ be, const int* __restrict__ batch,
                                                 float* __restrict__ gsum, float* __restrict__ gcnt,
                                                 int n, float invN) {
    __shared__ float ssc[64], ssh[64];
    if (threadIdx.x < 64) {
        int j = threadIdx.x;
        float mean = usum[j] * invN;
        float var = usq[j] * invN - mean * mean;
        float inv = rsqrtf(var + 1e-5f);
        float sc = inv * g[j];
        ssc[j] = sc;
        ssh[j] = fmaf(-mean, sc, be[j]);
    }
    __syncthreads();
    int lane = threadIdx.x & 63;
    int gw = (blockIdx.x * 256 + threadIdx.x) >> 6;
    int nw = (gridDim.x * 256) >> 6;
    int per = (n + nw - 1) / nw;
    int start = gw * per;
    int end = start + per; if (end > n) end = n;
    if (start >= end) return;
    float sc = ssc[lane], sh = ssh[lane];
    int cur = batch[start];
    float acc = 0.0f, c = 0.0f;
    for (int i = start; i < end; i++) {
        int b = batch[i];
        if (b != cur) {
            atomicAdd(&gsum[(size_t)cur * 64 + lane], acc);
            if (lane == 0) atomicAdd(&gcnt[cur], c);
            cur = b; acc = 0.0f; c = 0.0f;
        }
        float y = fmaf(u[(size_t)i * 64 + lane], sc, sh);
        acc += silu_f(y);
        c += 1.0f;
    }
    atomicAdd(&gsum[(size_t)cur * 64 + lane], acc);
    if (lane == 0) atomicAdd(&gcnt[cur], c);
}

// ---------- output ----------
__global__ __launch_bounds__(256) void k_out(const float* __restrict__ gsum, const float* __restrict__ gcnt,
                                             const float* __restrict__ OW, const float* __restrict__ ob,
                                             float* __restrict__ out, int G) {
    __shared__ float sW[4096];
    for (int i = threadIdx.x; i < 4096; i += 256) sW[i] = OW[i];
    __syncthreads();
    int lane = threadIdx.x & 63;
    int gw = (blockIdx.x * 256 + threadIdx.x) >> 6;
    int nw = (gridDim.x * 256) >> 6;
    for (int g = gw; g < G; g += nw) {
        int gu = rfl(g);
        float c = gcnt[gu]; if (c < 1.0f) c = 1.0f;
        float ci = 1.0f / c;
        float acc = ob[lane];
        const float* gr = gsum + (size_t)gu * 64;
        #pragma unroll
        for (int k = 0; k < 64; k++) acc = fmaf(gr[k] * ci, sW[k * 64 + lane], acc);
        out[(size_t)gu * 64 + lane] = silu_f(acc);
    }
}

extern "C" void kernel_launch(void* const* d_in, const int* in_sizes, int n_in,
                              void* d_out, int out_size, void* d_ws, size_t ws_size,
                              hipStream_t stream) {
    const int N = NN, E = EE, G = GG, L = LL;
    const float* x         = (const float*)d_in[0];
    const float* edge_attr = (const float*)d_in[1];
    const int*   edge_index= (const int*)d_in[2];
    const int*   batch     = (const int*)d_in[3];
    const float* node_W    = (const float*)d_in[4];
    const float* node_b    = (const float*)d_in[5];
    const float* msg_W1    = (const float*)d_in[6];
    const float* msg_b1    = (const float*)d_in[7];
    const float* msg_g1    = (const float*)d_in[8];
    const float* msg_be1   = (const float*)d_in[9];
    const float* msg_W2    = (const float*)d_in[10];
    const float* msg_b2    = (const float*)d_in[11];
    const float* upd_W     = (const float*)d_in[12];
    const float* upd_b     = (const float*)d_in[13];
    const float* upd_g     = (const float*)d_in[14];
    const float* upd_be    = (const float*)d_in[15];
    const float* out_W     = (const float*)d_in[16];
    const float* out_b     = (const float*)d_in[17];
    float* out = (float*)d_out;

    char* ws = (char*)d_ws;
    size_t off = 0;
    auto alloc = [&](size_t b) { size_t o = off; off = (off + b + 255) & ~(size_t)255; return o; };
    float* h    = (float*)(ws + alloc((size_t)N * 64 * 4));
    float* Hd   = (float*)(ws + alloc((size_t)N * 64 * 4));   // reused as u
    _Float16* Hs = (_Float16*)(ws + alloc((size_t)N * 64 * 2));
    float* sacc = (float*)(ws + alloc((size_t)N * 64 * 4));
    unsigned int* edata = (unsigned int*)(ws + alloc((size_t)E * 4));
    int* posb   = (int*)  (ws + alloc((size_t)E * 4));
    int* rowptr = (int*)  (ws + alloc((size_t)(N + 1) * 4));
    float* degf = (float*)(ws + alloc((size_t)N * 4));
    float* W2p  = (float*)(ws + alloc((size_t)L * 4096 * 4));
    float* b2p  = (float*)(ws + alloc((size_t)L * 64 * 4));
    int* bsum   = (int*)  (ws + alloc((size_t)256 * 4));
    size_t zero_begin = off;
    int*   fill = (int*)  (ws + alloc((size_t)N * 4));
    float* stats= (float*)(ws + alloc((size_t)L * 4 * 64 * 4));
    float* gsum = (float*)(ws + alloc((size_t)(G * 64 + G) * 4));
    size_t zero_end = off;
    float* gcnt = gsum + (size_t)G * 64;
    float* u = Hd;

    hipMemsetAsync(ws + zero_begin, 0, zero_end - zero_begin, stream);

    // CSR build (atomic-free scatter via posb from hist)
    const int SB = (N + 255) / 256;
    k_hist<<<(E + 255) / 256, 256, 0, stream>>>(edge_index, fill, posb, E);
    k_scan_blk<<<SB, 256, 0, stream>>>(fill, rowptr, degf, bsum, N);
    k_scan_top<<<1, 256, 0, stream>>>(bsum, SB);
    k_scan_add<<<SB, 256, 0, stream>>>(bsum, rowptr, N);
    k_scatter<<<(E + 255) / 256, 256, 0, stream>>>(edge_index, edge_attr, rowptr, posb, edata, E);

    // weight fold + node embedding
    k_fold<<<L, 256, 0, stream>>>(msg_W2, msg_b2, upd_W, W2p, b2p);
    k_node_emb<<<1024, 256, 0, stream>>>(x, node_W, node_b, h, N);

    // layer 0 pre
    k_node_pre<<<1024, 256, 0, stream>>>(h, msg_W1, msg_b1, Hd, Hs, N);

    for (int l = 0; l < L; l++) {
        const float* W1  = msg_W1 + (size_t)l * 129 * 64;
        const float* w1e = W1 + 128 * 64;
        float* esum = stats + (size_t)l * 256;
        float* esq  = esum + 64;
        float* usum = esum + 128;
        float* usq  = esum + 192;
        k_edge_stats<<<4096, 256, 0, stream>>>(Hd, Hs, rowptr, edata, w1e, esum, esq, N);
        k_edge_agg<<<2048, 256, 0, stream>>>(Hd, Hs, rowptr, edata, w1e, esum, esq,
                                             msg_g1 + l * 64, msg_be1 + l * 64, degf, sacc, N, 1.0f / E);
        k_node_upd<<<1024, 256, 0, stream>>>(h, sacc, rowptr, upd_W + (size_t)l * 8192,
                                             W2p + (size_t)l * 4096, b2p + (size_t)l * 64, upd_b + l * 64,
                                             u, usum, usq, N);
        if (l < L - 1) {
            const float* W1n = msg_W1 + (size_t)(l + 1) * 129 * 64;
            k_bn_pre<<<1024, 256, 0, stream>>>(u, usum, usq, upd_g + l * 64, upd_be + l * 64,
                                               W1n, msg_b1 + (l + 1) * 64, h, Hd, Hs, N, 1.0f / N);
        } else {
            k_bn_pool<<<256, 256, 0, stream>>>(u, usum, usq, upd_g + l * 64, upd_be + l * 64,
                                               batch, gsum, gcnt, N, 1.0f / N);
        }
    }

    k_out<<<64, 256, 0, stream>>>(gsum, gcnt, out_W, out_b, out, G);
}

// Round 8
// 1138.531 us; speedup vs baseline: 1.2093x; 1.2093x over previous
//
#include <hip/hip_runtime.h>
#include <hip/hip_bf16.h>

#define NN 50000
#define EE 1200000
#define GG 256
#define LL 5

// fast silu
__device__ __forceinline__ float silu_f(float x) {
    return x * __builtin_amdgcn_rcpf(1.0f + __expf(-x));
}
__device__ __forceinline__ int rfl(int x) { return __builtin_amdgcn_readfirstlane(x); }

// ---------- CSR build ----------
__global__ __launch_bounds__(256) void k_hist(const int* __restrict__ ei, int* __restrict__ fill, int E) {
    int e = blockIdx.x * 256 + threadIdx.x;
    if (e < E) atomicAdd(&fill[ei[E + e]], 1);
}

__global__ __launch_bounds__(256) void k_scan_blk(int* __restrict__ fill, int* __restrict__ rowptr,
                                                  float* __restrict__ degf, int* __restrict__ bsum, int n) {
    __shared__ int wsum[4];
    int tid = threadIdx.x, lane = tid & 63, wid = tid >> 6;
    int i = blockIdx.x * 256 + tid;
    int v = (i < n) ? fill[i] : 0;
    int x = v;
    #pragma unroll
    for (int off = 1; off < 64; off <<= 1) {
        int t = __shfl_up(x, off);
        if (lane >= off) x += t;
    }
    if (lane == 63) wsum[wid] = x;
    __syncthreads();
    int waveoff = 0;
    if (wid > 0) waveoff += wsum[0];
    if (wid > 1) waveoff += wsum[1];
    if (wid > 2) waveoff += wsum[2];
    int inc = x + waveoff;
    if (i < n) {
        rowptr[i + 1] = inc;
        degf[i] = (float)(v > 0 ? v : 1);
        fill[i] = 0;
    }
    if (tid == 255) bsum[blockIdx.x] = inc;
}

__global__ __launch_bounds__(256) void k_scan_top(int* __restrict__ bsum, int B) {
    __shared__ int wsum[4];
    int tid = threadIdx.x, lane = tid & 63, wid = tid >> 6;
    int v = (tid < B) ? bsum[tid] : 0;
    int x = v;
    #pragma unroll
    for (int off = 1; off < 64; off <<= 1) {
        int t = __shfl_up(x, off);
        if (lane >= off) x += t;
    }
    if (lane == 63) wsum[wid] = x;
    __syncthreads();
    int waveoff = 0;
    if (wid > 0) waveoff += wsum[0];
    if (wid > 1) waveoff += wsum[1];
    if (wid > 2) waveoff += wsum[2];
    if (tid < B) bsum[tid] = x + waveoff;
}

__global__ __launch_bounds__(256) void k_scan_add(const int* __restrict__ bsum, int* __restrict__ rowptr, int n) {
    int b = blockIdx.x;
    int i = b * 256 + threadIdx.x;
    if (i < n) {
        int add = (b > 0) ? bsum[b - 1] : 0;
        rowptr[i + 1] += add;
    }
    if (i == 0) rowptr[0] = 0;
}

__global__ __launch_bounds__(256) void k_scatter(const int* __restrict__ ei, const float* __restrict__ ea,
                                                 const int* __restrict__ rowptr, int* __restrict__ fill,
                                                 unsigned int* __restrict__ edata, int E) {
    int e = blockIdx.x * 256 + threadIdx.x;
    if (e < E) {
        int d = ei[E + e];
        int pos = atomicAdd(&fill[d], 1);
        int idx = rowptr[d] + pos;
        int ea15 = (int)(ea[e] * 32768.0f + 0.5f);
        if (ea15 > 32767) ea15 = 32767;
        edata[idx] = ((unsigned int)ea15 << 17) | (unsigned int)ei[e];
    }
}

// ---------- weight fold ----------
__global__ __launch_bounds__(256) void k_fold(const float* __restrict__ msg_W2, const float* __restrict__ msg_b2,
                                              const float* __restrict__ upd_W, float* __restrict__ W2p,
                                              float* __restrict__ b2p) {
    int l = blockIdx.x;
    const float* W2 = msg_W2 + (size_t)l * 4096;
    const float* U2 = upd_W + (size_t)l * 8192 + 4096;
    int lane = threadIdx.x & 63, wid = threadIdx.x >> 6;
    for (int ii = 0; ii < 16; ii++) {
        int i = rfl(wid * 16 + ii);
        float acc = 0.0f;
        for (int k = 0; k < 64; k++) acc = fmaf(W2[i * 64 + k], U2[k * 64 + lane], acc);
        W2p[(size_t)l * 4096 + i * 64 + lane] = acc;
    }
    if (wid == 0) {
        float acc = 0.0f;
        for (int k = 0; k < 64; k++) acc = fmaf(msg_b2[l * 64 + k], U2[k * 64 + lane], acc);
        b2p[l * 64 + lane] = acc;
    }
}

// ---------- node embedding: coalesced x staging via LDS ----------
__global__ __launch_bounds__(256) void k_node_emb(const float* __restrict__ x, const float* __restrict__ W,
                                                  const float* __restrict__ b, float* __restrict__ h, int n) {
    __shared__ float sW[92 * 64];
    __shared__ float sX[4][736];
    for (int i = threadIdx.x; i < 92 * 64; i += 256) sW[i] = W[i];
    __syncthreads();
    int lane = threadIdx.x & 63, wid = threadIdx.x >> 6;
    int gw = (blockIdx.x * 256 + threadIdx.x) >> 6;
    int nw = (gridDim.x * 256) >> 6;
    float bj = b[lane];
    int tiles = n >> 3;
    for (int t = gw; t < tiles; t += nw) {
        int rb = rfl(t << 3);
        const float4* xb = (const float4*)(x + (size_t)rb * 92);
        float4* sx4 = (float4*)&sX[wid][0];
        sx4[lane] = xb[lane];
        sx4[lane + 64] = xb[lane + 64];
        if (lane < 56) sx4[lane + 128] = xb[lane + 128];
        float acc[8];
        #pragma unroll
        for (int r = 0; r < 8; r++) acc[r] = bj;
        for (int kb = 0; kb < 80; kb += 16) {
            float wv[16];
            #pragma unroll
            for (int t2 = 0; t2 < 16; t2++) wv[t2] = sW[(kb + t2) * 64 + lane];
            #pragma unroll
            for (int r = 0; r < 8; r++) {
                #pragma unroll
                for (int t2 = 0; t2 < 16; t2++) acc[r] = fmaf(sX[wid][r * 92 + kb + t2], wv[t2], acc[r]);
            }
        }
        {
            float wv[12];
            #pragma unroll
            for (int t2 = 0; t2 < 12; t2++) wv[t2] = sW[(80 + t2) * 64 + lane];
            #pragma unroll
            for (int r = 0; r < 8; r++) {
                #pragma unroll
                for (int t2 = 0; t2 < 12; t2++) acc[r] = fmaf(sX[wid][r * 92 + 80 + t2], wv[t2], acc[r]);
            }
        }
        #pragma unroll
        for (int r = 0; r < 8; r++) h[(size_t)(rb + r) * 64 + lane] = acc[r];
    }
}

// ---------- layer 0 pre: Hd = h@W1[0:64]+b1 (fp32) ; Hs = h@W1[64:128] (fp16); staged h ----------
__global__ __launch_bounds__(256) void k_node_pre(const float* __restrict__ h, const float* __restrict__ W1,
                                                  const float* __restrict__ b1, float* __restrict__ Hd,
                                                  _Float16* __restrict__ Hs, int n) {
    __shared__ float sA[4096], sB[4096];
    __shared__ float sH[4][512];
    for (int i = threadIdx.x; i < 4096; i += 256) { sA[i] = W1[i]; sB[i] = W1[4096 + i]; }
    __syncthreads();
    int lane = threadIdx.x & 63, wid = threadIdx.x >> 6;
    int gw = (blockIdx.x * 256 + threadIdx.x) >> 6;
    int nw = (gridDim.x * 256) >> 6;
    float bj = b1[lane];
    int tiles = n >> 3;
    for (int t = gw; t < tiles; t += nw) {
        int rb = rfl(t << 3);
        const float4* hb = (const float4*)(h + (size_t)rb * 64);
        float4* sh4 = (float4*)&sH[wid][0];
        sh4[lane] = hb[lane];
        sh4[lane + 64] = hb[lane + 64];
        float accA[8], accB[8];
        #pragma unroll
        for (int r = 0; r < 8; r++) { accA[r] = bj; accB[r] = 0.0f; }
        for (int kb = 0; kb < 64; kb += 8) {
            float wA[8], wB[8];
            #pragma unroll
            for (int t2 = 0; t2 < 8; t2++) { wA[t2] = sA[(kb + t2) * 64 + lane]; wB[t2] = sB[(kb + t2) * 64 + lane]; }
            #pragma unroll
            for (int r = 0; r < 8; r++) {
                #pragma unroll
                for (int t2 = 0; t2 < 8; t2++) {
                    float hk = sH[wid][r * 64 + kb + t2];
                    accA[r] = fmaf(hk, wA[t2], accA[r]);
                    accB[r] = fmaf(hk, wB[t2], accB[r]);
                }
            }
        }
        #pragma unroll
        for (int r = 0; r < 8; r++) {
            Hd[(size_t)(rb + r) * 64 + lane] = accA[r];
            Hs[(size_t)(rb + r) * 64 + lane] = (_Float16)accB[r];
        }
    }
}

// ---------- fused BN+SiLU + next-layer pre (layers 1..4) ----------
__global__ __launch_bounds__(256) void k_bn_pre(const float* __restrict__ u, const float* __restrict__ usum,
                                                const float* __restrict__ usq, const float* __restrict__ g,
                                                const float* __restrict__ be, const float* __restrict__ W1,
                                                const float* __restrict__ b1, float* __restrict__ h,
                                                float* __restrict__ Hd, _Float16* __restrict__ Hs,
                                                int n, float invN) {
    __shared__ float sA[4096], sB[4096];
    __shared__ float sH[4][8][64];
    for (int i = threadIdx.x; i < 4096; i += 256) { sA[i] = W1[i]; sB[i] = W1[4096 + i]; }
    __syncthreads();
    int lane = threadIdx.x & 63, wid = threadIdx.x >> 6;
    float mean = usum[lane] * invN;
    float var = usq[lane] * invN - mean * mean;
    float inv = rsqrtf(var + 1e-5f);
    float sc = inv * g[lane];
    float sh = fmaf(-mean, sc, be[lane]);
    float bj = b1[lane];
    int gw = (blockIdx.x * 256 + threadIdx.x) >> 6;
    int nw = (gridDim.x * 256) >> 6;
    int tiles = n >> 3;
    for (int t = gw; t < tiles; t += nw) {
        int rb = rfl(t << 3);
        #pragma unroll
        for (int r = 0; r < 8; r++) {
            float uv = u[(size_t)(rb + r) * 64 + lane];
            float hv = silu_f(fmaf(uv, sc, sh));
            h[(size_t)(rb + r) * 64 + lane] = hv;
            sH[wid][r][lane] = hv;
        }
        float accA[8], accB[8];
        #pragma unroll
        for (int r = 0; r < 8; r++) { accA[r] = bj; accB[r] = 0.0f; }
        for (int k = 0; k < 64; k += 2) {
            float wA0 = sA[k * 64 + lane],       wB0 = sB[k * 64 + lane];
            float wA1 = sA[(k + 1) * 64 + lane], wB1 = sB[(k + 1) * 64 + lane];
            #pragma unroll
            for (int r = 0; r < 8; r++) {
                float h0 = sH[wid][r][k], h1 = sH[wid][r][k + 1];
                accA[r] = fmaf(h0, wA0, accA[r]);
                accB[r] = fmaf(h0, wB0, accB[r]);
                accA[r] = fmaf(h1, wA1, accA[r]);
                accB[r] = fmaf(h1, wB1, accB[r]);
            }
        }
        #pragma unroll
        for (int r = 0; r < 8; r++) {
            Hd[(size_t)(rb + r) * 64 + lane] = accA[r];
            Hs[(size_t)(rb + r) * 64 + lane] = (_Float16)accB[r];
        }
    }
}

// ---------- edge pass 1: sum(z), sum(z^2); 16-deep pipelined gather ----------
__global__ __launch_bounds__(256) void k_edge_stats(const float* __restrict__ Hd, const _Float16* __restrict__ Hs,
                                                    const int* __restrict__ rowptr, const unsigned int* __restrict__ edata,
                                                    const float* __restrict__ w1e,
                                                    float* __restrict__ esum, float* __restrict__ esq, int n) {
    __shared__ float rs[4][64], rq[4][64];
    int wid = threadIdx.x >> 6, lane = threadIdx.x & 63;
    int gw = (blockIdx.x * 256 + threadIdx.x) >> 6;
    int nw = (gridDim.x * 256) >> 6;
    float wj = w1e[lane] * (1.0f / 32768.0f);
    float s = 0.0f, q = 0.0f;
    for (int node = gw; node < n; node += nw) {
        int nu = rfl(node);
        int e0 = rfl(rowptr[nu]), e1 = rfl(rowptr[nu + 1]);
        if (e0 == e1) continue;
        float hd = Hd[(size_t)nu * 64 + lane];
        int nc = (e1 - e0) >> 4;
        int e = e0 + (nc << 4);
        if (nc > 0) {
            unsigned int pc[16];
            #pragma unroll
            for (int j = 0; j < 16; j++) pc[j] = edata[e0 + j];
            int eb = e0 + 16;
            for (int c = 0; c < nc - 1; c++, eb += 16) {
                float hs[16], av[16];
                #pragma unroll
                for (int j = 0; j < 16; j++) {
                    int sidx = rfl((int)(pc[j] & 0x1FFFFu));
                    av[j] = (float)rfl((int)(pc[j] >> 17));
                    hs[j] = (float)Hs[(size_t)sidx * 64 + lane];
                }
                #pragma unroll
                for (int j = 0; j < 16; j++) pc[j] = edata[eb + j];
                #pragma unroll
                for (int j = 0; j < 16; j++) {
                    float z = fmaf(av[j], wj, hd) + hs[j];
                    s += z;
                    q = fmaf(z, z, q);
                }
            }
            {
                float hs[16], av[16];
                #pragma unroll
                for (int j = 0; j < 16; j++) {
                    int sidx = rfl((int)(pc[j] & 0x1FFFFu));
                    av[j] = (float)rfl((int)(pc[j] >> 17));
                    hs[j] = (float)Hs[(size_t)sidx * 64 + lane];
                }
                #pragma unroll
                for (int j = 0; j < 16; j++) {
                    float z = fmaf(av[j], wj, hd) + hs[j];
                    s += z;
                    q = fmaf(z, z, q);
                }
            }
        }
        if (e + 8 <= e1) {
            float hs[8], av[8];
            #pragma unroll
            for (int j = 0; j < 8; j++) {
                unsigned int p = edata[e + j];
                int sidx = rfl((int)(p & 0x1FFFFu));
                av[j] = (float)rfl((int)(p >> 17));
                hs[j] = (float)Hs[(size_t)sidx * 64 + lane];
            }
            #pragma unroll
            for (int j = 0; j < 8; j++) {
                float z = fmaf(av[j], wj, hd) + hs[j];
                s += z;
                q = fmaf(z, z, q);
            }
            e += 8;
        }
        for (; e < e1; e++) {
            unsigned int p = edata[e];
            int sidx = rfl((int)(p & 0x1FFFFu));
            float a = (float)rfl((int)(p >> 17));
            float z = fmaf(a, wj, hd) + (float)Hs[(size_t)sidx * 64 + lane];
            s += z;
            q = fmaf(z, z, q);
        }
    }
    rs[wid][lane] = s; rq[wid][lane] = q;
    __syncthreads();
    if (wid == 0) {
        float ts = rs[0][lane] + rs[1][lane] + rs[2][lane] + rs[3][lane];
        float tq = rq[0][lane] + rq[1][lane] + rq[2][lane] + rq[3][lane];
        atomicAdd(&esum[lane], ts);
        atomicAdd(&esq[lane], tq);
    }
}

// ---------- fused edge pass 2 + node update; 16-deep pipelined gather ----------
// 4-row tiles; LDS = 32768 (weights) + 8192 (sHA) = 40960 -> 4 blocks/CU.
__global__ __launch_bounds__(256) void k_agg_upd(const float* __restrict__ Hd, const _Float16* __restrict__ Hs,
                                                 const int* __restrict__ rowptr, const unsigned int* __restrict__ edata,
                                                 const float* __restrict__ w1e,
                                                 const float* __restrict__ esum, const float* __restrict__ esq,
                                                 const float* __restrict__ g1, const float* __restrict__ be1,
                                                 const float* __restrict__ degf,
                                                 const float* __restrict__ h, const float* __restrict__ U1,
                                                 const float* __restrict__ W2p, const float* __restrict__ b2p,
                                                 const float* __restrict__ ub,
                                                 float* __restrict__ u, float* __restrict__ usum,
                                                 float* __restrict__ usq, int n, float invE) {
    __shared__ float sU[4096], sP[4096];
    __shared__ float2 sHA[4][4][64];
    for (int i = threadIdx.x; i < 4096; i += 256) { sU[i] = U1[i]; sP[i] = W2p[i]; }
    __syncthreads();
    int lane = threadIdx.x & 63, wid = threadIdx.x >> 6;
    float mean = esum[lane] * invE;
    float var = esq[lane] * invE - mean * mean;
    float inv = rsqrtf(var + 1e-5f);
    float sc = inv * g1[lane];
    float sh = fmaf(-mean, sc, be1[lane]);
    float wj = w1e[lane] * (1.0f / 32768.0f);
    float b2j = b2p[lane], ubj = ub[lane];
    int gw = (blockIdx.x * 256 + threadIdx.x) >> 6;
    int nw = (gridDim.x * 256) >> 6;
    float s = 0.0f, q = 0.0f;
    int tiles = n >> 2;
    for (int t = gw; t < tiles; t += nw) {
        int rb = rfl(t << 2);
        float gate[4];
        for (int r = 0; r < 4; r++) {
            int nu = rb + r;
            int e0 = rfl(rowptr[nu]), e1 = rfl(rowptr[nu + 1]);
            gate[r] = (e1 > e0) ? 1.0f : 0.0f;
            float hd = Hd[(size_t)nu * 64 + lane];
            float hvv = h[(size_t)nu * 64 + lane];   // issue early, consumed at row end
            float acc = 0.0f;
            int nc = (e1 - e0) >> 4;
            int e = e0 + (nc << 4);
            if (nc > 0) {
                unsigned int pc[16];
                #pragma unroll
                for (int j = 0; j < 16; j++) pc[j] = edata[e0 + j];
                int eb = e0 + 16;
                for (int c = 0; c < nc - 1; c++, eb += 16) {
                    float hs[16], av[16];
                    #pragma unroll
                    for (int j = 0; j < 16; j++) {
                        int sidx = rfl((int)(pc[j] & 0x1FFFFu));
                        av[j] = (float)rfl((int)(pc[j] >> 17));
                        hs[j] = (float)Hs[(size_t)sidx * 64 + lane];
                    }
                    #pragma unroll
                    for (int j = 0; j < 16; j++) pc[j] = edata[eb + j];
                    #pragma unroll
                    for (int j = 0; j < 16; j++) {
                        float z = fmaf(av[j], wj, hd) + hs[j];
                        acc += silu_f(fmaf(z, sc, sh));
                    }
                }
                {
                    float hs[16], av[16];
                    #pragma unroll
                    for (int j = 0; j < 16; j++) {
                        int sidx = rfl((int)(pc[j] & 0x1FFFFu));
                        av[j] = (float)rfl((int)(pc[j] >> 17));
                        hs[j] = (float)Hs[(size_t)sidx * 64 + lane];
                    }
                    #pragma unroll
                    for (int j = 0; j < 16; j++) {
                        float z = fmaf(av[j], wj, hd) + hs[j];
                        acc += silu_f(fmaf(z, sc, sh));
                    }
                }
            }
            if (e + 8 <= e1) {
                float hs[8], av[8];
                #pragma unroll
                for (int j = 0; j < 8; j++) {
                    unsigned int p = edata[e + j];
                    int sidx = rfl((int)(p & 0x1FFFFu));
                    av[j] = (float)rfl((int)(p >> 17));
                    hs[j] = (float)Hs[(size_t)sidx * 64 + lane];
                }
                #pragma unroll
                for (int j = 0; j < 8; j++) {
                    float z = fmaf(av[j], wj, hd) + hs[j];
                    acc += silu_f(fmaf(z, sc, sh));
                }
                e += 8;
            }
            for (; e < e1; e++) {
                unsigned int p = edata[e];
                int sidx = rfl((int)(p & 0x1FFFFu));
                float a = (float)rfl((int)(p >> 17));
                float z = fmaf(a, wj, hd) + (float)Hs[(size_t)sidx * 64 + lane];
                acc += silu_f(fmaf(z, sc, sh));
            }
            sHA[wid][r][lane] = make_float2(hvv, acc / degf[nu]);
        }
        // --- dual GEMM from LDS ---
        float accu[4];
        #pragma unroll
        for (int r = 0; r < 4; r++) accu[r] = fmaf(gate[r], b2j, ubj);
        for (int k = 0; k < 64; k++) {
            float wU = sU[k * 64 + lane], wP = sP[k * 64 + lane];
            #pragma unroll
            for (int r = 0; r < 4; r++) {
                float2 ha = sHA[wid][r][k];
                accu[r] = fmaf(ha.x, wU, accu[r]);
                accu[r] = fmaf(ha.y, wP, accu[r]);
            }
        }
        #pragma unroll
        for (int r = 0; r < 4; r++) {
            u[(size_t)(rb + r) * 64 + lane] = accu[r];
            s += accu[r];
            q = fmaf(accu[r], accu[r], q);
        }
    }
    // stats reduce via scratch aliased into this wave's sHA region
    {
        float* my = (float*)&sHA[wid][0][0];
        my[lane] = s;
        my[64 + lane] = q;
    }
    __syncthreads();
    if (wid == 0) {
        float ts = 0.0f, tq = 0.0f;
        #pragma unroll
        for (int w = 0; w < 4; w++) {
            const float* b = (const float*)&sHA[w][0][0];
            ts += b[lane];
            tq += b[64 + lane];
        }
        atomicAdd(&usum[lane], ts);
        atomicAdd(&usq[lane], tq);
    }
}

// ---------- layer-4 BN + SiLU fused with pooling ----------
__global__ __launch_bounds__(256) void k_bn_pool(const float* __restrict__ u, const float* __restrict__ usum,
                                                 const float* __restrict__ usq, const float* __restrict__ g,
                                                 const float* __restrict__ be, const int* __restrict__ batch,
                                                 float* __restrict__ gsum, float* __restrict__ gcnt,
                                                 int n, float invN) {
    __shared__ float ssc[64], ssh[64];
    if (threadIdx.x < 64) {
        int j = threadIdx.x;
        float mean = usum[j] * invN;
        float var = usq[j] * invN - mean * mean;
        float inv = rsqrtf(var + 1e-5f);
        float sc = inv * g[j];
        ssc[j] = sc;
        ssh[j] = fmaf(-mean, sc, be[j]);
    }
    __syncthreads();
    int lane = threadIdx.x & 63;
    int gw = (blockIdx.x * 256 + threadIdx.x) >> 6;
    int nw = (gridDim.x * 256) >> 6;
    int per = (n + nw - 1) / nw;
    int start = gw * per;
    int end = start + per; if (end > n) end = n;
    if (start >= end) return;
    float sc = ssc[lane], sh = ssh[lane];
    int cur = batch[start];
    float acc = 0.0f, c = 0.0f;
    for (int i = start; i < end; i++) {
        int b = batch[i];
        if (b != cur) {
            atomicAdd(&gsum[(size_t)cur * 64 + lane], acc);
            if (lane == 0) atomicAdd(&gcnt[cur], c);
            cur = b; acc = 0.0f; c = 0.0f;
        }
        float y = fmaf(u[(size_t)i * 64 + lane], sc, sh);
        acc += silu_f(y);
        c += 1.0f;
    }
    atomicAdd(&gsum[(size_t)cur * 64 + lane], acc);
    if (lane == 0) atomicAdd(&gcnt[cur], c);
}

// ---------- output ----------
__global__ __launch_bounds__(256) void k_out(const float* __restrict__ gsum, const float* __restrict__ gcnt,
                                             const float* __restrict__ OW, const float* __restrict__ ob,
                                             float* __restrict__ out, int G) {
    __shared__ float sW[4096];
    for (int i = threadIdx.x; i < 4096; i += 256) sW[i] = OW[i];
    __syncthreads();
    int lane = threadIdx.x & 63;
    int gw = (blockIdx.x * 256 + threadIdx.x) >> 6;
    int nw = (gridDim.x * 256) >> 6;
    for (int g = gw; g < G; g += nw) {
        int gu = rfl(g);
        float c = gcnt[gu]; if (c < 1.0f) c = 1.0f;
        float ci = 1.0f / c;
        float acc = ob[lane];
        const float* gr = gsum + (size_t)gu * 64;
        #pragma unroll
        for (int k = 0; k < 64; k++) acc = fmaf(gr[k] * ci, sW[k * 64 + lane], acc);
        out[(size_t)gu * 64 + lane] = silu_f(acc);
    }
}

extern "C" void kernel_launch(void* const* d_in, const int* in_sizes, int n_in,
                              void* d_out, int out_size, void* d_ws, size_t ws_size,
                              hipStream_t stream) {
    const int N = NN, E = EE, G = GG, L = LL;
    const float* x         = (const float*)d_in[0];
    const float* edge_attr = (const float*)d_in[1];
    const int*   edge_index= (const int*)d_in[2];
    const int*   batch     = (const int*)d_in[3];
    const float* node_W    = (const float*)d_in[4];
    const float* node_b    = (const float*)d_in[5];
    const float* msg_W1    = (const float*)d_in[6];
    const float* msg_b1    = (const float*)d_in[7];
    const float* msg_g1    = (const float*)d_in[8];
    const float* msg_be1   = (const float*)d_in[9];
    const float* msg_W2    = (const float*)d_in[10];
    const float* msg_b2    = (const float*)d_in[11];
    const float* upd_W     = (const float*)d_in[12];
    const float* upd_b     = (const float*)d_in[13];
    const float* upd_g     = (const float*)d_in[14];
    const float* upd_be    = (const float*)d_in[15];
    const float* out_W     = (const float*)d_in[16];
    const float* out_b     = (const float*)d_in[17];
    float* out = (float*)d_out;

    char* ws = (char*)d_ws;
    size_t off = 0;
    auto alloc = [&](size_t b) { size_t o = off; off = (off + b + 255) & ~(size_t)255; return o; };
    float* h    = (float*)(ws + alloc((size_t)N * 64 * 4));
    float* Hd   = (float*)(ws + alloc((size_t)N * 64 * 4));   // reused as u
    _Float16* Hs = (_Float16*)(ws + alloc((size_t)N * 64 * 2));
    unsigned int* edata = (unsigned int*)(ws + alloc((size_t)E * 4));
    int* rowptr = (int*)  (ws + alloc((size_t)(N + 1) * 4));
    float* degf = (float*)(ws + alloc((size_t)N * 4));
    float* W2p  = (float*)(ws + alloc((size_t)L * 4096 * 4));
    float* b2p  = (float*)(ws + alloc((size_t)L * 64 * 4));
    int* bsum   = (int*)  (ws + alloc((size_t)256 * 4));
    size_t zero_begin = off;
    int*   fill = (int*)  (ws + alloc((size_t)N * 4));
    float* stats= (float*)(ws + alloc((size_t)L * 4 * 64 * 4));
    float* gsum = (float*)(ws + alloc((size_t)(G * 64 + G) * 4));
    size_t zero_end = off;
    float* gcnt = gsum + (size_t)G * 64;
    float* u = Hd;

    hipMemsetAsync(ws + zero_begin, 0, zero_end - zero_begin, stream);

    // CSR build
    const int SB = (N + 255) / 256;
    k_hist<<<(E + 255) / 256, 256, 0, stream>>>(edge_index, fill, E);
    k_scan_blk<<<SB, 256, 0, stream>>>(fill, rowptr, degf, bsum, N);
    k_scan_top<<<1, 256, 0, stream>>>(bsum, SB);
    k_scan_add<<<SB, 256, 0, stream>>>(bsum, rowptr, N);
    k_scatter<<<(E + 255) / 256, 256, 0, stream>>>(edge_index, edge_attr, rowptr, fill, edata, E);

    // weight fold + node embedding
    k_fold<<<L, 256, 0, stream>>>(msg_W2, msg_b2, upd_W, W2p, b2p);
    k_node_emb<<<1024, 256, 0, stream>>>(x, node_W, node_b, h, N);

    // layer 0 pre
    k_node_pre<<<1024, 256, 0, stream>>>(h, msg_W1, msg_b1, Hd, Hs, N);

    for (int l = 0; l < L; l++) {
        const float* W1  = msg_W1 + (size_t)l * 129 * 64;
        const float* w1e = W1 + 128 * 64;
        float* esum = stats + (size_t)l * 256;
        float* esq  = esum + 64;
        float* usum = esum + 128;
        float* usq  = esum + 192;
        k_edge_stats<<<2048, 256, 0, stream>>>(Hd, Hs, rowptr, edata, w1e, esum, esq, N);
        k_agg_upd<<<1024, 256, 0, stream>>>(Hd, Hs, rowptr, edata, w1e, esum, esq,
                                            msg_g1 + l * 64, msg_be1 + l * 64, degf,
                                            h, upd_W + (size_t)l * 8192, W2p + (size_t)l * 4096,
                                            b2p + (size_t)l * 64, upd_b + l * 64,
                                            u, usum, usq, N, 1.0f / E);
        if (l < L - 1) {
            const float* W1n = msg_W1 + (size_t)(l + 1) * 129 * 64;
            k_bn_pre<<<1024, 256, 0, stream>>>(u, usum, usq, upd_g + l * 64, upd_be + l * 64,
                                               W1n, msg_b1 + (l + 1) * 64, h, Hd, Hs, N, 1.0f / N);
        } else {
            k_bn_pool<<<256, 256, 0, stream>>>(u, usum, usq, upd_g + l * 64, upd_be + l * 64,
                                               batch, gsum, gcnt, N, 1.0f / N);
        }
    }

    k_out<<<64, 256, 0, stream>>>(gsum, gcnt, out_W, out_b, out, G);
}